// Round 4
// baseline (296.694 us; speedup 1.0000x reference)
//
#include <hip/hip_runtime.h>
#include <hip/hip_bf16.h>

#define HH 4096      // canvas side
#define KK 32        // box / tile side
#define OH 4065      // HH - KK + 1
#define NB 225       // output cols per band (256 input cols - 31)
#define BC 256       // input cols per block == threads
#define RCHUNK 32    // output rows per block
#define GR 8         // output rows per LDS group
#define NSUB (RCHUNK / GR)   // 4 groups

// Barrier draining ONLY LDS (lgkmcnt). Global prefetch loads stay in flight.
__device__ __forceinline__ void barrier_lds_only() {
    asm volatile("" ::: "memory");
    __builtin_amdgcn_s_waitcnt(0xC07F);   // vmcnt(63) expcnt(7) lgkmcnt(0)
    __builtin_amdgcn_s_barrier();
    asm volatile("" ::: "memory");
}

__global__ __launch_bounds__(BC, 8) void som_fused(
    const float* __restrict__ img,   // 32x32
    const float* __restrict__ som,   // 4096x4096
    const float* __restrict__ var,   // 4096x4096
    float* __restrict__ out)         // 4065x4065
{
    __shared__ float simg[KK * KK];   // 4 KB
    __shared__ float ldsv[GR][BC];    // 8 KB, single buffer

    const int tid  = threadIdx.x;
    const int lane = tid & 63;
    const int wv   = tid >> 6;

    for (int i = tid; i < KK * KK; i += BC) simg[i] = img[i];
    __syncthreads();

    const int c0   = blockIdx.x * NB;
    const int col  = c0 + tid;
    const int colc = col < HH ? col : HH - 1;   // clamp (last band only)
    const int jc   = col & (KK - 1);
    const int r0   = blockIdx.y * RCHUNK;       // multiple of 32
    const int maxoff = HH - 1 - r0;
    const int cnt  = min(NB, OH - c0);          // valid output cols this band

    const float* sp = som + (size_t)r0 * HH + colc;
    const float* vp = var + (size_t)r0 * HH + colc;

    // ---- init vertical window: rows r0 .. r0+31 (always < 4096) ----
    float ring[KK];
    float sum = 0.f;
#pragma unroll
    for (int t = 0; t < KK; ++t) {
        const float s  = sp[t * HH];
        const float v  = vp[t * HH];
        const float im = simg[(t << 5) | jc];   // (r0+t)&31 == t
        const float e  = im - s;
        const float d  = e * e * __builtin_amdgcn_rcpf(v + 1e-8f);
        ring[t] = d;
        sum += d;
    }

    // ---- prefetch group 0 (rows r0+32 .. r0+39, clamped) ----
    float pf_s[2][GR], pf_v[2][GR];
#pragma unroll
    for (int k = 0; k < GR; ++k) {
        int off = KK + k;
        off = off <= maxoff ? off : maxoff;
        pf_s[0][k] = sp[off * HH];
        pf_v[0][k] = vp[off * HH];
    }

#pragma unroll
    for (int sub = 0; sub < NSUB; ++sub) {
        const int buf = sub & 1;

        // ---- prefetch group sub+1 into the other bank (static skip on last) ----
        if (sub + 1 < NSUB) {
#pragma unroll
            for (int k = 0; k < GR; ++k) {
                int off = KK + (sub + 1) * GR + k;
                off = off <= maxoff ? off : maxoff;
                pf_s[buf ^ 1][k] = sp[off * HH];
                pf_v[buf ^ 1][k] = vp[off * HH];
            }
        }

        // ---- phase A: emit GR column sums, slide window ----
        // Each ring slot is consumed exactly once (RCHUNK==KK): no refill.
#pragma unroll
        for (int k = 0; k < GR; ++k) {
            ldsv[k][tid] = sum;                 // vsum for row r0+sub*GR+k
            const float s  = pf_s[buf][k];
            const float v  = pf_v[buf][k];
            const float im = simg[((sub * GR + k) << 5) | jc];
            const float e  = im - s;
            const float d  = e * e * __builtin_amdgcn_rcpf(v + 1e-8f);
            sum += d - ring[sub * GR + k];
        }
        barrier_lds_only();

        // ---- phase B: per-row prefix scan + windowed diff + direct store ----
#pragma unroll
        for (int rr = 0; rr < 2; ++rr) {
            const int k = 2 * wv + rr;
            float4 x = *(const float4*)&ldsv[k][lane * 4];
            const float p0 = x.x;
            const float p1 = p0 + x.y;
            const float p2 = p1 + x.z;
            const float p3 = p2 + x.w;
            float sc = p3;
#pragma unroll
            for (int off = 1; off < 64; off <<= 1) {
                const float t = __shfl_up(sc, off, 64);
                sc += (lane >= off) ? t : 0.f;
            }
            const float excl = sc - p3;
            const float P0 = p0 + excl, P1 = p1 + excl;
            const float P2 = p2 + excl, P3 = p3 + excl;   // P[4l..4l+3]

            const float A  = __shfl_down(P3, 7, 64);      // P[4l+31]
            const float B0 = __shfl_down(P0, 8, 64);      // P[4l+32]
            const float B1 = __shfl_down(P1, 8, 64);      // P[4l+33]
            const float B2 = __shfl_down(P2, 8, 64);      // P[4l+34]
            float L = __shfl_up(P3, 1, 64);               // P[4l-1]
            L = (lane == 0) ? 0.f : L;

            const int rout = r0 + sub * GR + k;
            if (rout < OH) {
                const int cb = lane * 4;
                float* op = out + (size_t)rout * OH + c0 + cb;
                if (cb + 0 < cnt) op[0] = A  - L;   // cols [4l   .. 4l+31]
                if (cb + 1 < cnt) op[1] = B0 - P0;  // cols [4l+1 .. 4l+32]
                if (cb + 2 < cnt) op[2] = B1 - P1;
                if (cb + 3 < cnt) op[3] = B2 - P2;
            }
        }
        barrier_lds_only();   // protect ldsv reuse by next group's phase A
    }
}

extern "C" void kernel_launch(void* const* d_in, const int* in_sizes, int n_in,
                              void* d_out, int out_size, void* d_ws, size_t ws_size,
                              hipStream_t stream) {
    (void)in_sizes; (void)n_in; (void)out_size; (void)d_ws; (void)ws_size;
    const float* img = (const float*)d_in[0];   // 32x32
    const float* som = (const float*)d_in[1];   // 4096x4096
    const float* var = (const float*)d_in[2];   // 4096x4096
    float* out = (float*)d_out;                 // 4065x4065

    dim3 blk(BC);
    dim3 grd((OH + NB - 1) / NB,                // 19 column bands
             (OH + RCHUNK - 1) / RCHUNK);       // 128 row chunks = 2432 blocks
    hipLaunchKernelGGL(som_fused, grd, blk, 0, stream, img, som, var, out);
}

// Round 5
// 237.750 us; speedup vs baseline: 1.2479x; 1.2479x over previous
//
#include <hip/hip_runtime.h>
#include <hip/hip_bf16.h>

#define HH 4096      // canvas side
#define KK 32        // box / tile side
#define OH 4065      // HH - KK + 1
#define NB 225       // output cols per band (256 input cols - 31)
#define BC 256       // input cols per block == threads
#define RCHUNK 32    // output rows per block
#define GR 8         // output rows per LDS group
#define NSUB (RCHUNK / GR)   // 4 groups

// Barrier draining ONLY LDS (lgkmcnt). Global prefetch loads stay in flight.
__device__ __forceinline__ void barrier_lds_only() {
    asm volatile("" ::: "memory");
    __builtin_amdgcn_s_waitcnt(0xC07F);   // vmcnt(63) expcnt(7) lgkmcnt(0)
    __builtin_amdgcn_s_barrier();
    asm volatile("" ::: "memory");
}

// launch_bounds(256,4): VGPR cap 128. (256,8) forced a 64-VGPR cap and the
// allocator spilled ring[]+pf[] to scratch: R4 showed WRITE_SIZE 277 MB
// (210 MB scratch) at VGPR_Count=32. Do NOT tighten this.
__global__ __launch_bounds__(BC, 4) void som_fused(
    const float* __restrict__ img,   // 32x32
    const float* __restrict__ som,   // 4096x4096
    const float* __restrict__ var,   // 4096x4096
    float* __restrict__ out)         // 4065x4065
{
    __shared__ float simg[KK * KK];   // 4 KB
    __shared__ float ldsv[GR][BC];    // 8 KB, single buffer

    const int tid  = threadIdx.x;
    const int lane = tid & 63;
    const int wv   = tid >> 6;

    for (int i = tid; i < KK * KK; i += BC) simg[i] = img[i];
    __syncthreads();

    const int c0   = blockIdx.x * NB;
    const int col  = c0 + tid;
    const int colc = col < HH ? col : HH - 1;   // clamp (last band only)
    const int jc   = col & (KK - 1);
    const int r0   = blockIdx.y * RCHUNK;       // multiple of 32
    const int maxoff = HH - 1 - r0;
    const int cnt  = min(NB, OH - c0);          // valid output cols this band

    const float* sp = som + (size_t)r0 * HH + colc;
    const float* vp = var + (size_t)r0 * HH + colc;

    // ---- init vertical window: rows r0 .. r0+31 (always < 4096) ----
    float ring[KK];
    float sum = 0.f;
#pragma unroll
    for (int t = 0; t < KK; ++t) {
        const float s  = sp[t * HH];
        const float v  = vp[t * HH];
        const float im = simg[(t << 5) | jc];   // (r0+t)&31 == t
        const float e  = im - s;
        const float d  = e * e * __builtin_amdgcn_rcpf(v + 1e-8f);
        ring[t] = d;
        sum += d;
    }

    // ---- prefetch group 0 (rows r0+32 .. r0+39, clamped) ----
    float pf_s[2][GR], pf_v[2][GR];
#pragma unroll
    for (int k = 0; k < GR; ++k) {
        int off = KK + k;
        off = off <= maxoff ? off : maxoff;
        pf_s[0][k] = sp[off * HH];
        pf_v[0][k] = vp[off * HH];
    }

#pragma unroll
    for (int sub = 0; sub < NSUB; ++sub) {
        const int buf = sub & 1;

        // ---- prefetch group sub+1 into the other bank (static skip on last) ----
        if (sub + 1 < NSUB) {
#pragma unroll
            for (int k = 0; k < GR; ++k) {
                int off = KK + (sub + 1) * GR + k;
                off = off <= maxoff ? off : maxoff;
                pf_s[buf ^ 1][k] = sp[off * HH];
                pf_v[buf ^ 1][k] = vp[off * HH];
            }
        }

        // ---- phase A: emit GR column sums, slide window ----
        // Each ring slot is consumed exactly once (RCHUNK==KK): no refill.
#pragma unroll
        for (int k = 0; k < GR; ++k) {
            ldsv[k][tid] = sum;                 // vsum for row r0+sub*GR+k
            const float s  = pf_s[buf][k];
            const float v  = pf_v[buf][k];
            const float im = simg[((sub * GR + k) << 5) | jc];
            const float e  = im - s;
            const float d  = e * e * __builtin_amdgcn_rcpf(v + 1e-8f);
            sum += d - ring[sub * GR + k];
        }
        barrier_lds_only();

        // ---- phase B: per-row prefix scan + windowed diff + direct store ----
#pragma unroll
        for (int rr = 0; rr < 2; ++rr) {
            const int k = 2 * wv + rr;
            float4 x = *(const float4*)&ldsv[k][lane * 4];
            const float p0 = x.x;
            const float p1 = p0 + x.y;
            const float p2 = p1 + x.z;
            const float p3 = p2 + x.w;
            float sc = p3;
#pragma unroll
            for (int off = 1; off < 64; off <<= 1) {
                const float t = __shfl_up(sc, off, 64);
                sc += (lane >= off) ? t : 0.f;
            }
            const float excl = sc - p3;
            const float P0 = p0 + excl, P1 = p1 + excl;
            const float P2 = p2 + excl, P3 = p3 + excl;   // P[4l..4l+3]

            const float A  = __shfl_down(P3, 7, 64);      // P[4l+31]
            const float B0 = __shfl_down(P0, 8, 64);      // P[4l+32]
            const float B1 = __shfl_down(P1, 8, 64);      // P[4l+33]
            const float B2 = __shfl_down(P2, 8, 64);      // P[4l+34]
            float L = __shfl_up(P3, 1, 64);               // P[4l-1]
            L = (lane == 0) ? 0.f : L;

            const int rout = r0 + sub * GR + k;
            if (rout < OH) {
                const int cb = lane * 4;
                float* op = out + (size_t)rout * OH + c0 + cb;
                // nontemporal: write-once output; keep som/var resident in L2/L3
                if (cb + 0 < cnt) __builtin_nontemporal_store(A  - L,  op + 0);
                if (cb + 1 < cnt) __builtin_nontemporal_store(B0 - P0, op + 1);
                if (cb + 2 < cnt) __builtin_nontemporal_store(B1 - P1, op + 2);
                if (cb + 3 < cnt) __builtin_nontemporal_store(B2 - P2, op + 3);
            }
        }
        barrier_lds_only();   // protect ldsv reuse by next group's phase A
    }
}

extern "C" void kernel_launch(void* const* d_in, const int* in_sizes, int n_in,
                              void* d_out, int out_size, void* d_ws, size_t ws_size,
                              hipStream_t stream) {
    (void)in_sizes; (void)n_in; (void)out_size; (void)d_ws; (void)ws_size;
    const float* img = (const float*)d_in[0];   // 32x32
    const float* som = (const float*)d_in[1];   // 4096x4096
    const float* var = (const float*)d_in[2];   // 4096x4096
    float* out = (float*)d_out;                 // 4065x4065

    dim3 blk(BC);
    dim3 grd((OH + NB - 1) / NB,                // 19 column bands
             (OH + RCHUNK - 1) / RCHUNK);       // 128 row chunks = 2432 blocks
    hipLaunchKernelGGL(som_fused, grd, blk, 0, stream, img, som, var, out);
}

// Round 7
// 201.581 us; speedup vs baseline: 1.4718x; 1.1794x over previous
//
#include <hip/hip_runtime.h>
#include <hip/hip_bf16.h>

#define HH 4096      // canvas side
#define KK 32        // box / tile side
#define OH 4065      // HH - KK + 1
#define NB 225       // output cols per band (256 input cols - 31)
#define BC 256       // input cols per block == threads
// RCHUNK == KK == 32 output rows per block (required by the A/B split)

typedef float vfloat4 __attribute__((ext_vector_type(4)));  // clang-native for nt-store

// Ring-free vertical sums. r0 is 32-aligned, so
//   vsum[r0+i] = A(i) + B(i),
//   A(i) = sum dist rows [r0+i .. r0+31]   (suffix, descending accumulator)
//   B(i) = sum dist rows [r0+32 .. r0+31+i] (prefix, ascending accumulator)
// Two scalar accumulators per thread -> no register arrays -> no spills
// (R4/R5 post-mortem: ring[32]+pf[32] spilled to scratch at every
// launch_bounds setting; WRITE_SIZE showed +97..210 MB of scratch traffic).
__global__ __launch_bounds__(BC, 4) void som_fused(
    const float* __restrict__ img,   // 32x32
    const float* __restrict__ som,   // 4096x4096
    const float* __restrict__ var,   // 4096x4096
    float* __restrict__ out)         // 4065x4065
{
    __shared__ float simg[KK * KK];   // 4 KB
    __shared__ float ldsv[KK][BC];    // 32 KB: vsum for the 32 output rows

    const int tid  = threadIdx.x;
    const int lane = tid & 63;
    const int wv   = tid >> 6;

    for (int i = tid; i < KK * KK; i += BC) simg[i] = img[i];
    __syncthreads();

    const int c0   = blockIdx.x * NB;
    const int col  = c0 + tid;
    const int colc = col < HH ? col : HH - 1;   // clamp (last band only; clamped
                                                // cols sit at tid>=46, never read
                                                // by valid windows: c+31 <= 45)
    const int jc   = col & (KK - 1);
    const int r0   = blockIdx.y * KK;           // 32-aligned
    const int maxoff = HH - 1 - r0;             // row-offset clamp (last chunk)
    const int cnt  = min(NB, OH - c0);          // valid output cols this band

    const float* sp = som + (size_t)r0 * HH + colc;
    const float* vp = var + (size_t)r0 * HH + colc;

    // ---- pass A: suffix sums, rows r0+31 down to r0 (offsets <= 31 <= maxoff) ----
    {
        float acc = 0.f;
#pragma unroll
        for (int i = KK - 1; i >= 0; --i) {
            const float s  = sp[i * HH];
            const float v  = vp[i * HH];
            const float im = simg[(i << 5) | jc];      // (r0+i)&31 == i
            const float e  = im - s;
            acc += e * e * __builtin_amdgcn_rcpf(v + 1e-8f);
            ldsv[i][tid] = acc;                        // A(i)
        }
    }

    // ---- pass B: prefix sums of next block, rows r0+32 .. r0+62 (clamped) ----
    // Clamped rows only affect i>=1 of the last chunk, whose outputs are >= OH.
    // Same thread owns column tid in both passes: no barrier needed before RMW.
    {
        float acc2 = 0.f;
#pragma unroll
        for (int i = 1; i < KK; ++i) {
            int off = KK - 1 + i;                      // 32 .. 62
            off = off <= maxoff ? off : maxoff;
            const float s  = sp[off * HH];
            const float v  = vp[off * HH];
            const float im = simg[((i - 1) << 5) | jc]; // (r0+31+i)&31 == i-1
            const float e  = im - s;
            acc2 += e * e * __builtin_amdgcn_rcpf(v + 1e-8f);
            ldsv[i][tid] += acc2;                      // A(i)+B(i) = vsum
        }
    }

    __syncthreads();   // single main barrier; all loads already consumed

    // ---- scan + horizontal window + store: 8 rows per wave ----
#pragma unroll
    for (int j = 0; j < KK / 4; ++j) {
        const int k = wv * (KK / 4) + j;
        float4 x = *(const float4*)&ldsv[k][lane * 4];
        const float p0 = x.x;
        const float p1 = p0 + x.y;
        const float p2 = p1 + x.z;
        const float p3 = p2 + x.w;
        float sc = p3;
#pragma unroll
        for (int off = 1; off < 64; off <<= 1) {
            const float t = __shfl_up(sc, off, 64);
            sc += (lane >= off) ? t : 0.f;
        }
        const float excl = sc - p3;
        const float P0 = p0 + excl, P1 = p1 + excl;
        const float P2 = p2 + excl, P3 = p3 + excl;    // P[4l .. 4l+3]

        const float A  = __shfl_down(P3, 7, 64);       // P[4l+31]
        const float B0 = __shfl_down(P0, 8, 64);       // P[4l+32]
        const float B1 = __shfl_down(P1, 8, 64);       // P[4l+33]
        const float B2 = __shfl_down(P2, 8, 64);       // P[4l+34]
        float L = __shfl_up(P3, 1, 64);                // P[4l-1]
        L = (lane == 0) ? 0.f : L;

        const int rout = r0 + k;
        if (rout < OH) {
            const int cb = lane * 4;
            float* op = out + (size_t)rout * OH + c0 + cb;
            if (cb + 3 < cnt) {
                // contiguous 16B/lane -> full-line streaming stores
                vfloat4 o;
                o.x = A - L; o.y = B0 - P0; o.z = B1 - P1; o.w = B2 - P2;
                __builtin_nontemporal_store(o, (vfloat4*)op);
            } else {
                if (cb + 0 < cnt) op[0] = A  - L;
                if (cb + 1 < cnt) op[1] = B0 - P0;
                if (cb + 2 < cnt) op[2] = B1 - P1;
                // cb+3 handled by vector path only
            }
        }
    }
}

extern "C" void kernel_launch(void* const* d_in, const int* in_sizes, int n_in,
                              void* d_out, int out_size, void* d_ws, size_t ws_size,
                              hipStream_t stream) {
    (void)in_sizes; (void)n_in; (void)out_size; (void)d_ws; (void)ws_size;
    const float* img = (const float*)d_in[0];   // 32x32
    const float* som = (const float*)d_in[1];   // 4096x4096
    const float* var = (const float*)d_in[2];   // 4096x4096
    float* out = (float*)d_out;                 // 4065x4065

    dim3 blk(BC);
    dim3 grd((OH + NB - 1) / NB,                // 19 column bands
             (OH + KK - 1) / KK);               // 128 row chunks = 2432 blocks
    hipLaunchKernelGGL(som_fused, grd, blk, 0, stream, img, som, var, out);
}